// Round 14
// baseline (290.466 us; speedup 1.0000x reference)
//
#include <hip/hip_runtime.h>
#include <math.h>

#define NHEADS 16
#define HDIM   64
#define HID    1024
#define BATCH  2
#define SEQ    2048
#define NX (BATCH*SEQ*HID)       // 4194304
#define NW (HID*HID)             // 1048576

typedef unsigned short u16;
typedef __attribute__((ext_vector_type(8))) short  bf16x8;   // 8 bf16 = 4 VGPR
typedef __attribute__((ext_vector_type(8))) unsigned short u16x8;
typedef __attribute__((ext_vector_type(4))) float  f32x4;

// ---------------------------------------------------------------------------
// Fragment-tiled layout ("FT"): operand rows r, inner dim k. Subtile =
// 16 rows x 32 k. Element (r,k) lives at
//   ((r>>4)*KB + (k>>5))*512 + ((k>>3)&3)*128 + (r&15)*8 + (k&7)     [u16]
// (KB = k-blocks per row-block row). A wave's MFMA fragment load
// (lane = quad*16+lx -> 16B) is then 64 lanes x 16B CONTIGUOUS.
// hi / lo planes are separate arrays (keeps lane stride 16B).
// ---------------------------------------------------------------------------

// v_perm-based split: hi pair = bytes[2,3] of each fp32 (truncated bf16),
// lo pair = bytes[2,3] of (p - hi) — numerically identical to shift form.
__device__ __forceinline__ void split8(const float* xf, bf16x8& hi, bf16x8& lo) {
    unsigned* hp = (unsigned*)&hi;
    unsigned* lp = (unsigned*)&lo;
#pragma unroll
    for (int j = 0; j < 4; j++) {
        const float p0 = xf[2 * j], p1 = xf[2 * j + 1];
        const unsigned u0 = __float_as_uint(p0);
        const unsigned u1 = __float_as_uint(p1);
        hp[j] = __builtin_amdgcn_perm(u1, u0, 0x07060302u);
        const float l0 = p0 - __uint_as_float(u0 & 0xFFFF0000u);
        const float l1 = p1 - __uint_as_float(u1 & 0xFFFF0000u);
        lp[j] = __builtin_amdgcn_perm(__float_as_uint(l1), __float_as_uint(l0), 0x07060302u);
    }
}
__device__ __forceinline__ void split1(float v, u16& h, u16& l) {
    unsigned u = __float_as_uint(v);
    h = (u16)(u >> 16);
    l = (u16)(__float_as_uint(v - __uint_as_float(u & 0xFFFF0000u)) >> 16);
}

// ---------------------------------------------------------------------------
// RoPE tables
// ---------------------------------------------------------------------------
__global__ void rope_tables_kernel(float* __restrict__ ct, float* __restrict__ st) {
    int idx = blockIdx.x * 256 + threadIdx.x;
    if (idx >= SEQ * HDIM) return;
    int s  = idx >> 6;
    int dh = idx & 63;
    int i  = dh & 31;
    float inv = exp2f(-(float)i * (13.28771237954945f / 32.0f));  // log2(10000)/32
    float fr  = (float)s * inv;
    ct[idx] = cosf(fr);
    st[idx] = sinf(fr);
}

// ---------------------------------------------------------------------------
// Pre-pass v2 (unchanged): one wave per 512-u16 subtile, coalesced 1KB
// wave-stores.
// ---------------------------------------------------------------------------
__global__ __launch_bounds__(256) void split_kernel(
    const float* __restrict__ X,
    const float* __restrict__ W0,
    const float* __restrict__ W1,
    const float* __restrict__ W2,
    u16* __restrict__ Xhi, u16* __restrict__ Xlo,
    u16* __restrict__ Whi, u16* __restrict__ Wlo)
{
    const int s = blockIdx.x * 4 + (threadIdx.x >> 6);
    const int l = threadIdx.x & 63;
    const int r = l & 15, q = l >> 4;
    const float* src; u16* dh; u16* dl; int so;
    if (s < 8192) { src = X; dh = Xhi; dl = Xlo; so = s; }
    else {
        const int wi = (s - 8192) >> 11;
        so = (s - 8192) & 2047;
        src = (wi == 0) ? W0 : ((wi == 1) ? W1 : W2);
        dh = Whi + (size_t)wi * NW;
        dl = Wlo + (size_t)wi * NW;
    }
    const int R0 = (so >> 5) << 4, K0 = (so & 31) << 5;
    const float* sp = src + (size_t)(R0 + r) * 1024 + K0 + q * 8;
    float v[8];
    *(float4*)&v[0] = *(const float4*)sp;
    *(float4*)&v[4] = *(const float4*)(sp + 4);
    u16x8 h8, l8;
#pragma unroll
    for (int e = 0; e < 8; e++) {
        u16 hh, ll;
        split1(v[e], hh, ll);
        h8[e] = hh; l8[e] = ll;
    }
    const size_t off = (size_t)so * 512 + l * 8;
    *(u16x8*)(dh + off) = h8;
    *(u16x8*)(dl + off) = l8;
}

// ---------------------------------------------------------------------------
// MFMA QKV GEMM v9 (unchanged from round 13): LDS-staged fragments,
// staging buffer overlays the proj-2 vtr transpose buffer, XCD n-ownership
// remap, s_setprio, linear staging pointers with benign final overread.
// ---------------------------------------------------------------------------
__global__ __launch_bounds__(256, 2) void qkv_mfma_kernel(
    const u16* __restrict__ Xhi, const u16* __restrict__ Xlo,
    const u16* __restrict__ Whi, const u16* __restrict__ Wlo,
    const float* __restrict__ ct, const float* __restrict__ st,
    u16* __restrict__ Qhi, u16* __restrict__ Qlo,
    u16* __restrict__ Khi, u16* __restrict__ Klo,
    u16* __restrict__ Vhi, u16* __restrict__ Vlo)
{
    __shared__ __align__(16) unsigned char SMEMRAW[64 * 129 * 4];  // 33024 B
    u16* SM = (u16*)SMEMRAW;                       // staging view: 16384 u16
    unsigned (*vtr)[129] = (unsigned (*)[129])SMEMRAW;  // epilogue view

    const int t    = threadIdx.x;
    const int lane = t & 63;
    const int w    = t >> 6;
    const int lx   = lane & 15;
    const int quad = lane >> 4;

    // XCD n-ownership remap (768 blocks, 1D): xcd = lid%8 owns n-panel xcd.
    const int lid  = blockIdx.x;
    const int xcd  = lid & 7;
    const int i_   = lid >> 3;          // 0..95
    const int proj = i_ % 3;
    const int mb   = i_ / 3;            // 0..31
    const int nb   = xcd;
    const int n0   = nb * 128;
    const int m0   = mb * 128;

    const u16* __restrict__ Wph = Whi + (size_t)proj * NW;

    const int am = (w & 1) * 64;
    const int bn = (w >> 1) * 64;
    const int lp = quad * 128 + lx * 8;        // lane part of frag offset

    // --- staging pointers: thread t covers subtile si = t>>6 (and si+4 via
    // +65536 offset), in-subtile offset (t&63)*8; +512 per 32-k step ---
    const int si  = t >> 6;
    const int sio = (t & 63) * 8;
    const u16* pA = Xhi + (size_t)((m0 >> 4) + si) * 32 * 512 + sio;
    const u16* pB = Wph + (size_t)((n0 >> 4) + si) * 32 * 512 + sio;
    u16x8 sreg[8];
    auto stage_load = [&]() {
        sreg[0] = *(const u16x8*)(pA);                            // A_hi si
        sreg[1] = *(const u16x8*)(pA + 65536);                    // A_hi si+4
        sreg[2] = *(const u16x8*)(pA + (size_t)NX);               // A_lo si
        sreg[3] = *(const u16x8*)(pA + (size_t)NX + 65536);       // A_lo si+4
        sreg[4] = *(const u16x8*)(pB);                            // B_hi si
        sreg[5] = *(const u16x8*)(pB + 65536);                    // B_hi si+4
        sreg[6] = *(const u16x8*)(pB + 3 * (size_t)NW);           // B_lo si
        sreg[7] = *(const u16x8*)(pB + 3 * (size_t)NW + 65536);   // B_lo si+4
        pA += 512; pB += 512;
    };

    f32x4 acc[4][4];
#pragma unroll
    for (int i = 0; i < 4; i++)
#pragma unroll
        for (int j = 0; j < 4; j++) acc[i][j] = (f32x4){0.f, 0.f, 0.f, 0.f};

    // LDS fragment bases: A_hi 0, A_lo 4096, B_hi 8192, B_lo 12288
    const int aoff = (w & 1) * 4 * 512;
    const int boff = 8192 + (w >> 1) * 4 * 512;

    stage_load();   // k-block 0

#pragma unroll 1
    for (int kt = 0; kt < HID; kt += 32) {
        __syncthreads();                       // prev step's reads done
        {
            const int L = t * 8;
            *(u16x8*)&SM[L]         = sreg[0];
            *(u16x8*)&SM[L + 2048]  = sreg[1];
            *(u16x8*)&SM[L + 4096]  = sreg[2];
            *(u16x8*)&SM[L + 6144]  = sreg[3];
            *(u16x8*)&SM[L + 8192]  = sreg[4];
            *(u16x8*)&SM[L + 10240] = sreg[5];
            *(u16x8*)&SM[L + 12288] = sreg[6];
            *(u16x8*)&SM[L + 14336] = sreg[7];
        }
        __syncthreads();                       // staging visible

        // issue next step's staging loads (consumed at next barrier;
        // final iteration overreads into the adjacent plane, never consumed)
        stage_load();

        bf16x8 cah[4], cal[4], cbh[4], cbl[4];
#pragma unroll
        for (int i = 0; i < 4; i++) {
            cah[i] = *(const bf16x8*)&SM[aoff + i * 512 + lp];
            cal[i] = *(const bf16x8*)&SM[4096 + aoff + i * 512 + lp];
        }
#pragma unroll
        for (int j = 0; j < 4; j++) {
            cbh[j] = *(const bf16x8*)&SM[boff + j * 512 + lp];
            cbl[j] = *(const bf16x8*)&SM[4096 + boff + j * 512 + lp];
        }

        __builtin_amdgcn_s_setprio(1);
#pragma unroll
        for (int j = 0; j < 4; j++)
#pragma unroll
            for (int i = 0; i < 4; i++) {
                acc[i][j] = __builtin_amdgcn_mfma_f32_16x16x32_bf16(cah[i], cbh[j], acc[i][j], 0, 0, 0);
                acc[i][j] = __builtin_amdgcn_mfma_f32_16x16x32_bf16(cal[i], cbh[j], acc[i][j], 0, 0, 0);
                acc[i][j] = __builtin_amdgcn_mfma_f32_16x16x32_bf16(cah[i], cbl[j], acc[i][j], 0, 0, 0);
            }
        __builtin_amdgcn_s_setprio(0);
    }

    // ---- epilogue ----
    const int b      = m0 >> 11;
    const int head   = (n0 >> 6) + (w >> 1);
    const int m_base = m0 + am;

    if (proj < 2) {
#pragma unroll
        for (int i = 0; i < 4; i++) {
#pragma unroll
            for (int r = 0; r < 4; r++) {
                const int s = (m_base + i * 16 + quad * 4 + r) & 2047;
                const float* ctr = ct + s * HDIM;
                const float* str = st + s * HDIM;
                float nv[4];
#pragma unroll
                for (int j = 0; j < 4; j++) {
                    const int dh = j * 16 + lx;
                    const float c  = ctr[dh];
                    const float sn = str[dh];
                    const float x  = acc[i][j][r];
                    const float p  = acc[i][j ^ 2][r];
                    nv[j] = (j < 2) ? (x * c - p * sn) : (x * c + p * sn);
                }
#pragma unroll
                for (int j = 0; j < 4; j++) acc[i][j][r] = nv[j];
            }
        }
        u16* dh_ = (proj == 0) ? Qhi : Khi;
        u16* dl_ = (proj == 0) ? Qlo : Klo;
        const float qscale = (proj == 0) ? 0.18033688011112042f : 1.0f;
        const size_t obase = (size_t)(b * NHEADS + head) * SEQ * HDIM;
#pragma unroll
        for (int i = 0; i < 4; i++)
#pragma unroll
            for (int r = 0; r < 4; r++) {
                const int s   = (m_base + i * 16 + quad * 4 + r) & 2047;
                const int rb  = s >> 4;
                const int lxq = s & 15;
#pragma unroll
                for (int j = 0; j < 4; j++) {
                    const size_t fo = obase + ((size_t)rb * 2 + (j >> 1)) * 512
                                    + (size_t)((j & 1) * 2 + (lx >> 3)) * 128
                                    + (size_t)lxq * 8 + (lx & 7);
                    u16 hh, ll;
                    split1(acc[i][j][r] * qscale, hh, ll);
                    dh_[fo] = hh;
                    dl_[fo] = ll;
                }
            }
    } else {
#pragma unroll 1
        for (int pass = 0; pass < 2; pass++) {
            __syncthreads();
            if ((w & 1) == pass) {
#pragma unroll
                for (int i = 0; i < 4; i++)
#pragma unroll
                    for (int j = 0; j < 4; j++)
#pragma unroll
                        for (int r = 0; r < 4; r++) {
                            const int ml = i * 16 + quad * 4 + r;
                            const int nl = bn + j * 16 + lx;
                            const float v = acc[i][j][r];
                            unsigned u  = __float_as_uint(v);
                            unsigned hi = u & 0xFFFF0000u;
                            unsigned lo = __float_as_uint(v - __uint_as_float(hi)) >> 16;
                            vtr[ml][nl] = hi | lo;
                        }
            }
            __syncthreads();
            {
                const int d      = t >> 1;            // 0..127 (2 heads x 64)
                const int sh     = (t & 1) * 32;
                const int headv  = (n0 >> 6) + (d >> 6);
                const int dd     = d & 63;
                const size_t vbase = (size_t)(b * NHEADS + headv) * SEQ * HDIM;
                const int s0base = (m0 & 2047) + pass * 64 + sh;
#pragma unroll
                for (int k = 0; k < 4; k++) {
                    const int s0 = s0base + k * 8;
                    u16x8 hv, lv;
#pragma unroll
                    for (int e = 0; e < 8; e++) {
                        unsigned u = vtr[sh + k * 8 + e][d];
                        hv[e] = (u16)(u >> 16);
                        lv[e] = (u16)(u & 0xFFFFu);
                    }
                    const size_t fo = vbase + ((size_t)(dd >> 4) * 64 + (s0 >> 5)) * 512
                                    + (size_t)((s0 >> 3) & 3) * 128 + (size_t)(dd & 15) * 8;
                    *(u16x8*)(Vhi + fo) = hv;
                    *(u16x8*)(Vlo + fo) = lv;
                }
            }
        }
    }
}

// ---------------------------------------------------------------------------
// Flash attention v14 = round-12 (verified 128 us) + Vlo staged in LDS as a
// 4th plane: the last 4x-redundant global path (8 b128 loads/wave/tile)
// becomes 2 staging chunks/thread + ds_read_b128 on the existing lgkmcnt
// schedule. LDS 59392 -> 67584 B, still 2 blocks/CU (135 KB < 160 KB).
// Everything else byte-identical to round 12.
// ---------------------------------------------------------------------------
__global__ __launch_bounds__(256, 2) void attn_kernel(
    const u16* __restrict__ Qhi, const u16* __restrict__ Qlo,
    const u16* __restrict__ Khi, const u16* __restrict__ Klo,
    const u16* __restrict__ Vhi, const u16* __restrict__ Vlo,
    float* __restrict__ OUT)
{
    __shared__ __align__(16) u16 KVs[4][4096];   // Khi, Klo, Vhi, Vlo (32 KB)
    __shared__ float PS[4][32][68];              // 34816 B

    const int t    = threadIdx.x;
    const int lane = t & 63;
    const int w    = t >> 6;
    const int lx   = lane & 15;
    const int quad = lane >> 4;

    const int q0 = blockIdx.x * 128;
    const int h  = blockIdx.y;
    const int b  = blockIdx.z;
    const size_t base = (size_t)(b * NHEADS + h) * SEQ * HDIM;
    const int lp = quad * 128 + lx * 8;

    // Q fragments (already split + pre-scaled in workspace)
    bf16x8 qh[2][2], ql[2][2];
#pragma unroll
    for (int a = 0; a < 2; a++)
#pragma unroll
        for (int ks = 0; ks < 2; ks++) {
            const size_t fo = base + ((size_t)((q0 >> 4) + w * 2 + a) * 2 + ks) * 512 + lp;
            qh[a][ks] = *(const bf16x8*)(Qhi + fo);
            ql[a][ks] = *(const bf16x8*)(Qlo + fo);
        }

    f32x4 O[2][4];
    float l_part[2][4];
#pragma unroll
    for (int a = 0; a < 2; a++) {
#pragma unroll
        for (int dt = 0; dt < 4; dt++) O[a][dt] = (f32x4){0.f,0.f,0.f,0.f};
#pragma unroll
        for (int r = 0; r < 4; r++) l_part[a][r] = 0.f;
    }

    // --- staging machinery: 8 chunks/thread (2 halves x 4 planes), linear
    // pointers with constant strides ---
    const int o0 = t * 8;            // [0,2048)
    const int o1 = o0 + 2048;        // [2048,4096)
    const u16* pKh0 = Khi + base + o0;
    const u16* pKh1 = Khi + base + o1;
    const u16* pKl0 = Klo + base + o0;
    const u16* pKl1 = Klo + base + o1;
    const u16* pVh0 = Vhi + base + ((size_t)(o0 >> 10) * 64) * 512 + (o0 & 1023);
    const u16* pVh1 = Vhi + base + ((size_t)(o1 >> 10) * 64) * 512 + (o1 & 1023);
    const u16* pVl0 = Vlo + base + ((size_t)(o0 >> 10) * 64) * 512 + (o0 & 1023);
    const u16* pVl1 = Vlo + base + ((size_t)(o1 >> 10) * 64) * 512 + (o1 & 1023);
    u16x8 sreg[8];
    auto stage_load = [&]() {
        sreg[0] = *(const u16x8*)pKh0;  pKh0 += 4096;   // K tile stride
        sreg[1] = *(const u16x8*)pKh1;  pKh1 += 4096;
        sreg[2] = *(const u16x8*)pKl0;  pKl0 += 4096;
        sreg[3] = *(const u16x8*)pKl1;  pKl1 += 4096;
        sreg[4] = *(const u16x8*)pVh0;  pVh0 += 1024;   // V tile stride
        sreg[5] = *(const u16x8*)pVh1;  pVh1 += 1024;
        sreg[6] = *(const u16x8*)pVl0;  pVl0 += 1024;
        sreg[7] = *(const u16x8*)pVl1;  pVl1 += 1024;
    };

    stage_load();

#pragma unroll 1
    for (int kt = 0; kt < SEQ; kt += 64) {
        __syncthreads();                       // prev body done reading KVs
        {
            *(u16x8*)&KVs[0][o0] = sreg[0];
            *(u16x8*)&KVs[0][o1] = sreg[1];
            *(u16x8*)&KVs[1][o0] = sreg[2];
            *(u16x8*)&KVs[1][o1] = sreg[3];
            *(u16x8*)&KVs[2][o0] = sreg[4];
            *(u16x8*)&KVs[2][o1] = sreg[5];
            *(u16x8*)&KVs[3][o0] = sreg[6];
            *(u16x8*)&KVs[3][o1] = sreg[7];
        }
        __syncthreads();                       // staging visible

        // issue next tile's staging loads (consumed at next barrier;
        // final iteration overreads into the adjacent plane, never consumed)
        stage_load();

        // ---- K fragments from LDS ----
        bf16x8 kh[2][4], kl[2][4];
#pragma unroll
        for (int c = 0; c < 4; c++)
#pragma unroll
            for (int ks = 0; ks < 2; ks++) {
                kh[ks][c] = *(const bf16x8*)&KVs[0][(c * 2 + ks) * 512 + lp];
                kl[ks][c] = *(const bf16x8*)&KVs[1][(c * 2 + ks) * 512 + lp];
            }

        // ---- scores + exp -> PS ----
#pragma unroll
        for (int a = 0; a < 2; a++) {
#pragma unroll
            for (int c = 0; c < 4; c++) {
                f32x4 acc = (f32x4){0.f,0.f,0.f,0.f};
                __builtin_amdgcn_s_setprio(1);
#pragma unroll
                for (int ks = 0; ks < 2; ks++) {
                    acc = __builtin_amdgcn_mfma_f32_16x16x32_bf16(qh[a][ks], kh[ks][c], acc, 0, 0, 0);
                    acc = __builtin_amdgcn_mfma_f32_16x16x32_bf16(ql[a][ks], kh[ks][c], acc, 0, 0, 0);
                    acc = __builtin_amdgcn_mfma_f32_16x16x32_bf16(qh[a][ks], kl[ks][c], acc, 0, 0, 0);
                }
                __builtin_amdgcn_s_setprio(0);
#pragma unroll
                for (int r = 0; r < 4; r++) {
                    float p = exp2f(acc[r]);           // Q pre-scaled: 2^(qk*log2e/8)
                    l_part[a][r] += p;
                    PS[w][a * 16 + quad * 4 + r][c * 16 + lx] = p;
                }
            }
        }

        // ---- V fragments from LDS (both planes) ----
        bf16x8 vh[2][4], vl[2][4];
#pragma unroll
        for (int dt = 0; dt < 4; dt++)
#pragma unroll
            for (int ks2 = 0; ks2 < 2; ks2++) {
                vh[ks2][dt] = *(const bf16x8*)&KVs[2][dt * 1024 + ks2 * 512 + lp];
                vl[ks2][dt] = *(const bf16x8*)&KVs[3][dt * 1024 + ks2 * 512 + lp];
            }

        // ---- PV ----
#pragma unroll
        for (int a = 0; a < 2; a++) {
#pragma unroll
            for (int ks2 = 0; ks2 < 2; ks2++) {
                const float* ps = &PS[w][a * 16 + lx][ks2 * 32 + quad * 8];
                float pf[8];
                *(float4*)&pf[0] = *(const float4*)ps;
                *(float4*)&pf[4] = *(const float4*)(ps + 4);
                bf16x8 phi, plo;
                split8(pf, phi, plo);
                __builtin_amdgcn_s_setprio(1);
#pragma unroll
                for (int dt = 0; dt < 4; dt++) {
                    O[a][dt] = __builtin_amdgcn_mfma_f32_16x16x32_bf16(phi, vh[ks2][dt], O[a][dt], 0, 0, 0);
                    O[a][dt] = __builtin_amdgcn_mfma_f32_16x16x32_bf16(plo, vh[ks2][dt], O[a][dt], 0, 0, 0);
                    O[a][dt] = __builtin_amdgcn_mfma_f32_16x16x32_bf16(phi, vl[ks2][dt], O[a][dt], 0, 0, 0);
                }
                __builtin_amdgcn_s_setprio(0);
            }
        }
    }

    float linv[2][4];
#pragma unroll
    for (int a = 0; a < 2; a++)
#pragma unroll
        for (int r = 0; r < 4; r++) {
            float l = l_part[a][r];
            l += __shfl_xor(l, 1);
            l += __shfl_xor(l, 2);
            l += __shfl_xor(l, 4);
            l += __shfl_xor(l, 8);
            linv[a][r] = 1.f / l;
        }

    float* Po = &PS[0][0][0];   // reuse as [128][68]
    __syncthreads();            // all waves done with their PS regions
#pragma unroll
    for (int a = 0; a < 2; a++)
#pragma unroll
        for (int dt = 0; dt < 4; dt++)
#pragma unroll
            for (int r = 0; r < 4; r++)
                Po[(size_t)(w * 32 + a * 16 + quad * 4 + r) * 68 + dt * 16 + lx] =
                    O[a][dt][r] * linv[a][r];
    __syncthreads();
    {
        const int q    = t >> 1;
        const int half = t & 1;
        const float* prow = Po + (size_t)q * 68 + half * 32;
        float* dst = OUT + ((size_t)(b * SEQ + q0 + q)) * HID + h * HDIM + half * 32;
#pragma unroll
        for (int e = 0; e < 8; e++)
            ((float4*)dst)[e] = ((const float4*)prow)[e];
    }
}

// ---------------------------------------------------------------------------
extern "C" void kernel_launch(void* const* d_in, const int* in_sizes, int n_in,
                              void* d_out, int out_size, void* d_ws, size_t ws_size,
                              hipStream_t stream)
{
    const float* X  = (const float*)d_in[0];
    const float* Wq = (const float*)d_in[1];
    const float* Wk = (const float*)d_in[2];
    const float* Wv = (const float*)d_in[3];
    float* out = (float*)d_out;

    const size_t qkv_elems = (size_t)BATCH * NHEADS * SEQ * HDIM;  // 4,194,304
    char* wsb = (char*)d_ws;
    float* ct  = (float*)wsb;                       // 0.5 MB
    float* st  = ct + (size_t)SEQ * HDIM;           // 0.5 MB
    u16* Xhi = (u16*)(st + (size_t)SEQ * HDIM);     // 8 MB
    u16* Xlo = Xhi + (size_t)NX;                    // 8 MB
    u16* Whi = Xlo + (size_t)NX;                    // 6 MB
    u16* Wlo = Whi + 3 * (size_t)NW;                // 6 MB
    u16* Qhi = Wlo + 3 * (size_t)NW;                // 8 MB
    u16* Qlo = Qhi + qkv_elems;                     // 8 MB
    u16* Khi = Qlo + qkv_elems;                     // 8 MB
    u16* Klo = Khi + qkv_elems;                     // 8 MB
    u16* Vhi = Klo + qkv_elems;                     // 8 MB
    u16* Vlo = Vhi + qkv_elems;                     // 8 MB   (total 77 MB)

    rope_tables_kernel<<<(SEQ * HDIM + 255) / 256, 256, 0, stream>>>(ct, st);

    // 14336 subtiles (8192 X + 3*2048 W), 4 per 256-thread block
    split_kernel<<<3584, 256, 0, stream>>>(
        X, Wq, Wk, Wv, Xhi, Xlo, Whi, Wlo);

    qkv_mfma_kernel<<<dim3(3 * (HID / 128) * ((BATCH * SEQ) / 128)), 256, 0, stream>>>(
        Xhi, Xlo, Whi, Wlo, ct, st, Qhi, Qlo, Khi, Klo, Vhi, Vlo);

    attn_kernel<<<dim3(SEQ / 128, NHEADS, BATCH), 256, 0, stream>>>(
        Qhi, Qlo, Khi, Klo, Vhi, Vlo, out);
}